// Round 12
// baseline (607.371 us; speedup 1.0000x reference)
//
#include <hip/hip_runtime.h>
#include <hip/hip_bf16.h>
#include <math.h>

#define NNODES 50000
#define NEDGES 500000
#define NTOT   (NEDGES + NNODES)   // 550000 edges incl. self-loops
#define MPAD   50048               // 391 * 128
#define D1     512
#define NH     4
#define LN_EPS 1e-5f
#define NEG_SLOPE 0.2f

#define SBLK 256
#define NSB  ((NNODES + SBLK - 1) / SBLK)   // 196

typedef __attribute__((ext_vector_type(8))) short short8;
typedef __attribute__((ext_vector_type(4))) float f32x4;
typedef __hip_bfloat16 bf16;

#define GLDS16(g, l) __builtin_amdgcn_global_load_lds( \
    (const __attribute__((address_space(1))) void*)(g), \
    (__attribute__((address_space(3))) void*)(l), 16, 0, 0)

__device__ __forceinline__ float bf2f(short u) {
    unsigned int x = ((unsigned int)(unsigned short)u) << 16;
    return __uint_as_float(x);
}
__device__ __forceinline__ short f2bf(float f) {   // RNE
    unsigned int x = __float_as_uint(f);
    unsigned int r = (x + 0x7fffu + ((x >> 16) & 1u)) >> 16;
    return (short)r;
}
__device__ __forceinline__ float leaky(float e) {
    return (e >= 0.f) ? e : NEG_SLOPE * e;
}

// bijective XCD-chunked remap (m204): consecutive work-ids land on one XCD,
// col-block fastest, so a panel's col-blocks share that XCD's L2 (A reuse).
__device__ __forceinline__ void xcd_map(int bid, int nwg, int ncolblk,
                                        int* p, int* c) {
    int q = nwg >> 3, r = nwg & 7;
    int xcd = bid & 7, j = bid >> 3;
    int w = (xcd < r) ? xcd * (q + 1) + j : r * (q + 1) + (xcd - r) * q + j;
    *p = w / ncolblk;
    *c = w - (*p) * ncolblk;
}

// ---------------- CSR build (counting sort by dst) ----------------

__global__ void k_count(const int* __restrict__ ei, int* __restrict__ counts) {
    int e = blockIdx.x * blockDim.x + threadIdx.x;
    if (e >= NTOT) return;
    int d = (e < NEDGES) ? ei[NEDGES + e] : (e - NEDGES);
    atomicAdd(&counts[d], 1);
}

__global__ void k_scan1(const int* __restrict__ counts, int* __restrict__ offs,
                        int* __restrict__ bsums) {
    __shared__ int s[SBLK];
    int tid = threadIdx.x, b = blockIdx.x;
    int idx = b * SBLK + tid;
    int v = (idx < NNODES) ? counts[idx] : 0;
    s[tid] = v;
    __syncthreads();
    for (int d = 1; d < SBLK; d <<= 1) {
        int t = (tid >= d) ? s[tid - d] : 0;
        __syncthreads();
        s[tid] += t;
        __syncthreads();
    }
    if (idx < NNODES) offs[idx] = s[tid] - v;   // local exclusive
    if (tid == SBLK - 1) bsums[b] = s[tid];
}

__global__ void k_scan2(const int* __restrict__ bsums, int* __restrict__ bbase) {
    __shared__ int s[256];
    int tid = threadIdx.x;
    int v = (tid < NSB) ? bsums[tid] : 0;
    s[tid] = v;
    __syncthreads();
    for (int d = 1; d < 256; d <<= 1) {
        int t = (tid >= d) ? s[tid - d] : 0;
        __syncthreads();
        s[tid] += t;
        __syncthreads();
    }
    bbase[tid] = s[tid] - v;                     // exclusive
    if (tid == 255) bbase[256] = s[255];         // total
}

__global__ void k_scan3(int* __restrict__ offs, const int* __restrict__ bbase,
                        int* __restrict__ cursor) {
    int idx = blockIdx.x * 256 + threadIdx.x;
    if (idx < NNODES) {
        int v = offs[idx] + bbase[idx >> 8];
        offs[idx] = v;
        cursor[idx] = v;
    }
    if (idx == 0) offs[NNODES] = bbase[256];
}

__global__ void k_fill(const int* __restrict__ ei, int* __restrict__ cursor,
                       int* __restrict__ srcs) {
    int e = blockIdx.x * blockDim.x + threadIdx.x;
    if (e >= NTOT) return;
    int s, d;
    if (e < NEDGES) { s = ei[e]; d = ei[NEDGES + e]; }
    else            { s = d = e - NEDGES; }
    int pos = atomicAdd(&cursor[d], 1);
    srcs[pos] = s;
}

// ---------------- conversions ----------------

__global__ void k_wt_all(const float* __restrict__ W1, const float* __restrict__ We1,
                         const float* __restrict__ We2, const float* __restrict__ Wr,
                         const float* __restrict__ W2, const float* __restrict__ Wc1,
                         bf16* __restrict__ W1t, bf16* __restrict__ We1t,
                         bf16* __restrict__ We2t, bf16* __restrict__ Wrt,
                         bf16* __restrict__ W2t, bf16* __restrict__ Wc1t) {
    int which = blockIdx.y;
    const float* W; bf16* Wt; int K, N, Kpad;
    switch (which) {
        case 0:  W = W1;  Wt = W1t;  K = 182; N = 512; Kpad = 192; break;
        case 1:  W = We1; Wt = We1t; K = 512; N = 512; Kpad = 512; break;
        case 2:  W = We2; Wt = We2t; K = 512; N = 256; Kpad = 512; break;
        case 3:  W = Wr;  Wt = Wrt;  K = 512; N = 256; Kpad = 512; break;
        case 4:  W = W2;  Wt = W2t;  K = 256; N = 512; Kpad = 256; break;
        default: W = Wc1; Wt = Wc1t; K = 512; N = 512; Kpad = 512; break;
    }
    int idx = blockIdx.x * 256 + threadIdx.x;
    if (idx >= N * Kpad) return;
    int n = idx / Kpad, k = idx % Kpad;
    float v = (k < K) ? W[(size_t)k * N + n] : 0.f;
    Wt[idx] = __float2bfloat16(v);
}

// vectorized: one short8 chunk per thread
__global__ void k_xconv(const float* __restrict__ x, bf16* __restrict__ xb) {
    int idx = blockIdx.x * 256 + threadIdx.x;
    if (idx >= MPAD * 24) return;          // 24 chunks of 8 per row
    int r = idx / 24, c8 = (idx % 24) * 8;
    short8 ov;
    #pragma unroll
    for (int j = 0; j < 8; j++) {
        int k = c8 + j;
        float v = (r < NNODES && k < 182) ? x[(size_t)r * 182 + k] : 0.f;
        ov[j] = f2bf(v);
    }
    *reinterpret_cast<short8*>(&xb[(size_t)r * 192 + c8]) = ov;
}

// ---- fold attention vectors into weights: wsd[k][j] (j<4: src, j>=4: dst) ----
// (validated R9: exact f32 fold, als = A @ wsd[:,0:4], ald = A @ wsd[:,4:8])

__global__ void k_wsd(const float* __restrict__ W1, const float* __restrict__ as1,
                      const float* __restrict__ ad1, const float* __restrict__ W2,
                      const float* __restrict__ as2, const float* __restrict__ ad2,
                      float* __restrict__ wsd1, float* __restrict__ wsd2) {
    int idx = blockIdx.x * 256 + threadIdx.x;   // 0..192*8+256*8-1
    if (idx < 192 * 8) {
        int k = idx >> 3, j = idx & 7;
        int hh = j & 3;
        float s = 0.f;
        if (k < 182) {
            const float* a = (j < 4) ? as1 : ad1;
            for (int c = 0; c < 128; c++)
                s += W1[(size_t)k * 512 + hh * 128 + c] * a[hh * 128 + c];
        }
        wsd1[idx] = s;
    } else if (idx < 192 * 8 + 256 * 8) {
        int i2 = idx - 192 * 8;
        int k = i2 >> 3, j = i2 & 7;
        int hh = j & 3;
        const float* a = (j < 4) ? as2 : ad2;
        float s = 0.f;
        for (int c = 0; c < 128; c++)
            s += W2[(size_t)k * 512 + hh * 128 + c] * a[hh * 128 + c];
        wsd2[i2] = s;
    }
}

// ---- pre-GEMM logits: wave per node, short8 loads, 64-lane shuffle reduce ----

__global__ __launch_bounds__(256) void k_logits_pre(
        const bf16* __restrict__ A, const float* __restrict__ wsd,
        float* __restrict__ als, float* __restrict__ ald, int K) {
    int tid = threadIdx.x;
    int n = blockIdx.x * 4 + (tid >> 6);
    if (n >= NNODES) return;
    int lane = tid & 63;
    int nch = K >> 3;
    float p[8] = {};
    if (lane < nch) {
        short8 hv = *reinterpret_cast<const short8*>(&A[(size_t)n * K + lane * 8]);
        #pragma unroll
        for (int e = 0; e < 8; e++) {
            float v = bf2f(hv[e]);
            const float* w = &wsd[(lane * 8 + e) * 8];
            #pragma unroll
            for (int j = 0; j < 8; j++) p[j] += v * w[j];
        }
    }
    #pragma unroll
    for (int j = 0; j < 8; j++)
        #pragma unroll
        for (int o = 1; o < 64; o <<= 1) p[j] += __shfl_xor(p[j], o);
    if (lane == 0) {
        #pragma unroll
        for (int j = 0; j < 4; j++) als[n * NH + j] = p[j];
        #pragma unroll
        for (int j = 0; j < 4; j++) ald[n * NH + j] = p[4 + j];
    }
}

// -------- per-edge softmax alpha (one wave per node, edge-parallel) ---------

__global__ __launch_bounds__(256) void k_edge_alpha(
        const float* __restrict__ als, const float* __restrict__ ald,
        const int* __restrict__ offs, const int* __restrict__ srcs,
        float* __restrict__ alpha) {
    int tid = threadIdx.x;
    int n = blockIdx.x * 4 + (tid >> 6);
    if (n >= NNODES) return;
    int lane = tid & 63;
    int head = lane >> 4, sub = lane & 15;
    int e0 = offs[n], e1 = offs[n + 1];
    float adh = ald[n * NH + head];

    float m = -1e30f;
    for (int k = e0 + sub; k < e1; k += 16)
        m = fmaxf(m, leaky(als[srcs[k] * NH + head] + adh));
    #pragma unroll
    for (int o = 1; o < 16; o <<= 1) m = fmaxf(m, __shfl_xor(m, o));
    float d = 0.f;
    for (int k = e0 + sub; k < e1; k += 16)
        d += __expf(leaky(als[srcs[k] * NH + head] + adh) - m);
    #pragma unroll
    for (int o = 1; o < 16; o <<= 1) d += __shfl_xor(d, o);
    float dinv = 1.f / d;
    for (int k = e0 + sub; k < e1; k += 16)
        alpha[k * NH + head] = __expf(leaky(als[srcs[k] * NH + head] + adh) - m) * dinv;
}

// ------ GAT aggregation + bias + LayerNorm + ELU (one wave per node) --------

__global__ __launch_bounds__(256) void k_gat_aggregate(
        const bf16* __restrict__ h, const float* __restrict__ alpha,
        const int* __restrict__ offs, const int* __restrict__ srcs,
        const float* __restrict__ bias, const float* __restrict__ gamma,
        const float* __restrict__ beta, bf16* __restrict__ out) {
    int tid = threadIdx.x;
    int n = blockIdx.x * 4 + (tid >> 6);
    if (n >= NNODES) return;
    int lane = tid & 63;
    int head = lane >> 4;
    int ch0 = lane * 8;
    int e0 = offs[n], e1 = offs[n + 1];

    float acc[8] = {};
    for (int base = e0; base < e1; base += 64) {
        int cnt = min(64, e1 - base);
        int sv = (base + lane < e1) ? srcs[base + lane] : 0;
        int k = 0;
        for (; k + 8 <= cnt; k += 8) {
            int ss[8]; float pp[8]; short8 hh[8];
            #pragma unroll
            for (int u = 0; u < 8; u++) {
                ss[u] = __shfl(sv, k + u);
                pp[u] = alpha[(base + k + u) * NH + head];
            }
            #pragma unroll
            for (int u = 0; u < 8; u++)
                hh[u] = *reinterpret_cast<const short8*>(&h[(size_t)ss[u] * D1 + ch0]);
            #pragma unroll
            for (int j = 0; j < 8; j++) {
                float a = 0.f;
                #pragma unroll
                for (int u = 0; u < 8; u++) a += pp[u] * bf2f(hh[u][j]);
                acc[j] += a;
            }
        }
        for (; k + 4 <= cnt; k += 4) {
            int s0 = __shfl(sv, k),     s1 = __shfl(sv, k + 1);
            int s2 = __shfl(sv, k + 2), s3 = __shfl(sv, k + 3);
            float p0 = alpha[(base + k)     * NH + head];
            float p1 = alpha[(base + k + 1) * NH + head];
            float p2 = alpha[(base + k + 2) * NH + head];
            float p3 = alpha[(base + k + 3) * NH + head];
            short8 h0 = *reinterpret_cast<const short8*>(&h[(size_t)s0 * D1 + ch0]);
            short8 h1 = *reinterpret_cast<const short8*>(&h[(size_t)s1 * D1 + ch0]);
            short8 h2 = *reinterpret_cast<const short8*>(&h[(size_t)s2 * D1 + ch0]);
            short8 h3 = *reinterpret_cast<const short8*>(&h[(size_t)s3 * D1 + ch0]);
            #pragma unroll
            for (int j = 0; j < 8; j++)
                acc[j] += p0 * bf2f(h0[j]) + p1 * bf2f(h1[j])
                        + p2 * bf2f(h2[j]) + p3 * bf2f(h3[j]);
        }
        for (; k < cnt; k++) {
            int s0 = __shfl(sv, k);
            float p0 = alpha[(base + k) * NH + head];
            short8 h0 = *reinterpret_cast<const short8*>(&h[(size_t)s0 * D1 + ch0]);
            #pragma unroll
            for (int j = 0; j < 8; j++) acc[j] += p0 * bf2f(h0[j]);
        }
    }

    float v[8];
    float ps = 0.f;
    #pragma unroll
    for (int j = 0; j < 8; j++) { v[j] = acc[j] + bias[ch0 + j]; ps += v[j]; }
    #pragma unroll
    for (int o = 1; o < 64; o <<= 1) ps += __shfl_xor(ps, o);
    float mu = ps * (1.f / 512.f);
    float qs = 0.f;
    #pragma unroll
    for (int j = 0; j < 8; j++) { float dvj = v[j] - mu; qs += dvj * dvj; }
    #pragma unroll
    for (int o = 1; o < 64; o <<= 1) qs += __shfl_xor(qs, o);
    float rstd = rsqrtf(qs * (1.f / 512.f) + LN_EPS);

    short8 ov;
    #pragma unroll
    for (int j = 0; j < 8; j++) {
        float y = (v[j] - mu) * rstd * gamma[ch0 + j] + beta[ch0 + j];
        float e = (y > 0.f) ? y : (__expf(y) - 1.f);
        ov[j] = f2bf(e);
    }
    *reinterpret_cast<short8*>(&out[(size_t)n * D1 + ch0]) = ov;
}

// ---------------- bf16 MFMA GEMM, BK=64, both-sides swizzled LDS ------------
// 1D grid + XCD-chunked block remap (T1): a panel's col-blocks colocate.

#define EPI_BF       0   // C -> bf16
#define EPI_BRELU_BF 1   // relu(C + bias) -> bf16
#define EPI_CLS      2   // atomicAdd(out, relu(C+bias) @ Wc2 (+bc2))

template<int EPI>
__global__ __launch_bounds__(256) void gemm64(
    const ushort* __restrict__ A, const ushort* __restrict__ Bt,
    const float* __restrict__ bias, bf16* __restrict__ Obf,
    float* __restrict__ Of32, const float* __restrict__ Wc2,
    int Mreal, int N, int K, const float* __restrict__ bc2, int ncolblk) {
    __shared__ __align__(16) ushort As[128 * 64];
    __shared__ __align__(16) ushort Bs[128 * 64];
    int tid = threadIdx.x;
    int wave = tid >> 6, lane = tid & 63;
    int pp, cc;
    xcd_map(blockIdx.x, gridDim.x, ncolblk, &pp, &cc);
    int brow = pp * 128;
    int bcol = cc * 128;
    int wm = (wave >> 1) * 64, wn = (wave & 1) * 64;
    int lr = lane & 15, hi = lane >> 4;
    int rx = lr & 7;                 // read-side row xor
    int r8 = lane >> 3;              // stage-side row within 8-row group
    int slotsw = (lane & 7) ^ r8;    // pre-swizzled 16B slot in global row

    f32x4 acc[4][4] = {};

    for (int k0 = 0; k0 < K; k0 += 64) {
        if (k0) __syncthreads();
        #pragma unroll
        for (int i = 0; i < 4; i++) {
            int rb = wave * 32 + i * 8;     // 8 rows per GLDS16 (1 KB)
            GLDS16(A  + (size_t)(brow + rb + r8) * K + k0 + slotsw * 8, As + rb * 64);
            GLDS16(Bt + (size_t)(bcol + rb + r8) * K + k0 + slotsw * 8, Bs + rb * 64);
        }
        __syncthreads();

        #pragma unroll
        for (int sub = 0; sub < 2; sub++) {
            short8 af[4], bfr[4];
            int bsl = ((sub * 4 + hi) ^ rx) * 8;
            #pragma unroll
            for (int f = 0; f < 4; f++) {
                af[f]  = *reinterpret_cast<const short8*>(&As[(wm + f * 16 + lr) * 64 + bsl]);
                bfr[f] = *reinterpret_cast<const short8*>(&Bs[(wn + f * 16 + lr) * 64 + bsl]);
            }
            #pragma unroll
            for (int fm = 0; fm < 4; fm++)
                #pragma unroll
                for (int fn = 0; fn < 4; fn++)
                    acc[fm][fn] = __builtin_amdgcn_mfma_f32_16x16x32_bf16(
                        af[fm], bfr[fn], acc[fm][fn], 0, 0, 0);
        }
    }

    if (EPI == EPI_CLS) {
        float w2[4][2], b4[4];
        #pragma unroll
        for (int fn = 0; fn < 4; fn++) {
            int col = bcol + wn + fn * 16 + lr;
            w2[fn][0] = Wc2[col * 2];
            w2[fn][1] = Wc2[col * 2 + 1];
            b4[fn] = bias[col];
        }
        #pragma unroll
        for (int fm = 0; fm < 4; fm++) {
            #pragma unroll
            for (int r = 0; r < 4; r++) {
                int row = brow + wm + fm * 16 + hi * 4 + r;
                float s0 = 0.f, s1 = 0.f;
                #pragma unroll
                for (int fn = 0; fn < 4; fn++) {
                    float v = acc[fm][fn][r] + b4[fn];
                    v = v > 0.f ? v : 0.f;
                    s0 += v * w2[fn][0];
                    s1 += v * w2[fn][1];
                }
                #pragma unroll
                for (int o = 1; o < 16; o <<= 1) {
                    s0 += __shfl_xor(s0, o);
                    s1 += __shfl_xor(s1, o);
                }
                if (lr == 0 && row < Mreal) {
                    if (bcol == 0 && wn == 0) { s0 += bc2[0]; s1 += bc2[1]; }
                    atomicAdd(&Of32[row * 2],     s0);
                    atomicAdd(&Of32[row * 2 + 1], s1);
                }
            }
        }
        return;
    }

    #pragma unroll
    for (int fm = 0; fm < 4; fm++) {
        int row0 = brow + wm + fm * 16 + hi * 4;
        #pragma unroll
        for (int fn = 0; fn < 4; fn++) {
            int col = bcol + wn + fn * 16 + lr;
            #pragma unroll
            for (int r = 0; r < 4; r++) {
                int row = row0 + r;
                if (row >= Mreal) continue;
                float v = acc[fm][fn][r];
                if (EPI == EPI_BRELU_BF) { v += bias[col]; v = v > 0.f ? v : 0.f; }
                Obf[(size_t)row * N + col] = __float2bfloat16(v);
            }
        }
    }
}

// ------- dual GEMM (BK=64): O = A2@B2t + rs*(A1@B1t) + (b2 + rs*b1) -> bf16 --

__global__ __launch_bounds__(256) void gemm_dual64(
    const ushort* __restrict__ A1, const ushort* __restrict__ B1t,   // t, We2t
    const ushort* __restrict__ A2, const ushort* __restrict__ B2t,   // h1, Wrt
    const float* __restrict__ bias1, const float* __restrict__ bias2,
    bf16* __restrict__ Obf, int Mreal, int N, int K,
    const float* __restrict__ rsc, int ncolblk) {
    __shared__ __align__(16) ushort As[128 * 64];
    __shared__ __align__(16) ushort Bs[128 * 64];
    int tid = threadIdx.x;
    int wave = tid >> 6, lane = tid & 63;
    int pp, cc;
    xcd_map(blockIdx.x, gridDim.x, ncolblk, &pp, &cc);
    int brow = pp * 128;
    int bcol = cc * 128;
    int wm = (wave >> 1) * 64, wn = (wave & 1) * 64;
    int lr = lane & 15, hi = lane >> 4;
    int rx = lr & 7;
    int r8 = lane >> 3;
    int slotsw = (lane & 7) ^ r8;
    float rs = *rsc;

    f32x4 acc[4][4] = {};

    #pragma unroll
    for (int phase = 0; phase < 2; phase++) {
        const ushort* Ap = phase ? A2 : A1;
        const ushort* Bp = phase ? B2t : B1t;
        if (phase) {
            __syncthreads();
            #pragma unroll
            for (int fm = 0; fm < 4; fm++)
                #pragma unroll
                for (int fn = 0; fn < 4; fn++)
                    #pragma unroll
                    for (int r = 0; r < 4; r++) acc[fm][fn][r] *= rs;
        }
        for (int k0 = 0; k0 < K; k0 += 64) {
            if (k0 || phase) __syncthreads();
            #pragma unroll
            for (int i = 0; i < 4; i++) {
                int rb = wave * 32 + i * 8;
                GLDS16(Ap + (size_t)(brow + rb + r8) * K + k0 + slotsw * 8, As + rb * 64);
                GLDS16(Bp + (size_t)(bcol + rb + r8) * K + k0 + slotsw * 8, Bs + rb * 64);
            }
            __syncthreads();

            #pragma unroll
            for (int sub = 0; sub < 2; sub++) {
                short8 af[4], bfr[4];
                int bsl = ((sub * 4 + hi) ^ rx) * 8;
                #pragma unroll
                for (int f = 0; f < 4; f++) {
                    af[f]  = *reinterpret_cast<const short8*>(&As[(wm + f * 16 + lr) * 64 + bsl]);
                    bfr[f] = *reinterpret_cast<const short8*>(&Bs[(wn + f * 16 + lr) * 64 + bsl]);
                }
                #pragma unroll
                for (int fm = 0; fm < 4; fm++)
                    #pragma unroll
                    for (int fn = 0; fn < 4; fn++)
                        acc[fm][fn] = __builtin_amdgcn_mfma_f32_16x16x32_bf16(
                            af[fm], bfr[fn], acc[fm][fn], 0, 0, 0);
            }
        }
    }

    #pragma unroll
    for (int fm = 0; fm < 4; fm++) {
        int row0 = brow + wm + fm * 16 + hi * 4;
        #pragma unroll
        for (int fn = 0; fn < 4; fn++) {
            int col = bcol + wn + fn * 16 + lr;
            float be = bias2[col] + rs * bias1[col];
            #pragma unroll
            for (int r = 0; r < 4; r++) {
                int row = row0 + r;
                if (row >= Mreal) continue;
                Obf[(size_t)row * N + col] = __float2bfloat16(acc[fm][fn][r] + be);
            }
        }
    }
}

// ---------------- launch ----------------

extern "C" void kernel_launch(void* const* d_in, const int* in_sizes, int n_in,
                              void* d_out, int out_size, void* d_ws, size_t ws_size,
                              hipStream_t stream) {
    const float* x   = (const float*)d_in[0];
    const int*   ei  = (const int*)d_in[1];
    const float* W1  = (const float*)d_in[2];
    const float* as1 = (const float*)d_in[3];
    const float* ad1 = (const float*)d_in[4];
    const float* b1  = (const float*)d_in[5];
    const float* g1  = (const float*)d_in[6];
    const float* bn1 = (const float*)d_in[7];
    const float* We1 = (const float*)d_in[8];
    const float* bE1 = (const float*)d_in[9];
    const float* We2 = (const float*)d_in[10];
    const float* bE2 = (const float*)d_in[11];
    const float* Wr  = (const float*)d_in[12];
    const float* br  = (const float*)d_in[13];
    const float* rsc = (const float*)d_in[14];
    const float* W2  = (const float*)d_in[15];
    const float* as2 = (const float*)d_in[16];
    const float* ad2 = (const float*)d_in[17];
    const float* b2  = (const float*)d_in[18];
    const float* g2  = (const float*)d_in[19];
    const float* bn2 = (const float*)d_in[20];
    const float* Wc1 = (const float*)d_in[21];
    const float* bc1 = (const float*)d_in[22];
    const float* Wc2 = (const float*)d_in[23];
    const float* bc2 = (const float*)d_in[24];
    float* out = (float*)d_out;

    char* ws = (char*)d_ws;
    size_t o = 0;
    auto alloc = [&](size_t bytes) { void* p = ws + o; o += (bytes + 255) & ~255ull; return p; };
    bf16* xb    = (bf16*)alloc((size_t)MPAD * 192 * 2);
    bf16* bufA  = (bf16*)alloc((size_t)MPAD * D1 * 2);   // h (per layer)
    bf16* bufB  = (bf16*)alloc((size_t)MPAD * D1 * 2);   // h1, h2
    bf16* bufC  = (bf16*)alloc((size_t)MPAD * D1 * 2);   // t (expansion)
    bf16* hcb   = (bf16*)alloc((size_t)MPAD * 256 * 2);  // h_comb bf16
    bf16* W1t   = (bf16*)alloc((size_t)512 * 192 * 2);
    bf16* We1t  = (bf16*)alloc((size_t)512 * 512 * 2);
    bf16* We2t  = (bf16*)alloc((size_t)256 * 512 * 2);
    bf16* Wrt   = (bf16*)alloc((size_t)256 * 512 * 2);
    bf16* W2t   = (bf16*)alloc((size_t)512 * 256 * 2);
    bf16* Wc1t  = (bf16*)alloc((size_t)512 * 512 * 2);
    float* wsd1 = (float*)alloc(192 * 8 * 4);
    float* wsd2 = (float*)alloc(256 * 8 * 4);
    float* als  = (float*)alloc((size_t)NNODES * NH * 4);
    float* ald  = (float*)alloc((size_t)NNODES * NH * 4);
    float* alpha= (float*)alloc((size_t)NTOT * NH * 4);
    int* counts = (int*)alloc((NNODES + 1) * 4);
    int* offs   = (int*)alloc((NNODES + 1) * 4);
    int* cursor = (int*)alloc((NNODES + 1) * 4);
    int* srcs   = (int*)alloc((size_t)NTOT * 4);
    int* bsums  = (int*)alloc((NSB + 1) * 4);
    int* bbase  = (int*)alloc(257 * 4);

    // CSR by dst (shared by both GAT layers)
    hipMemsetAsync(counts, 0, NNODES * 4, stream);
    k_count<<<(NTOT + 255) / 256, 256, 0, stream>>>(ei, counts);
    k_scan1<<<NSB, SBLK, 0, stream>>>(counts, offs, bsums);
    k_scan2<<<1, 256, 0, stream>>>(bsums, bbase);
    k_scan3<<<(NNODES + 255) / 256, 256, 0, stream>>>(offs, bbase, cursor);
    k_fill<<<(NTOT + 255) / 256, 256, 0, stream>>>(ei, cursor, srcs);

    // weight + input conversion, folded attention weights
    k_wt_all<<<dim3(1024, 6), 256, 0, stream>>>(W1, We1, We2, Wr, W2, Wc1,
                                                W1t, We1t, We2t, Wrt, W2t, Wc1t);
    k_xconv<<<(MPAD * 24 + 255) / 256, 256, 0, stream>>>(x, xb);
    k_wsd<<<14, 256, 0, stream>>>(W1, as1, ad1, W2, as2, ad2, wsd1, wsd2);

    dim3 blk(256);
    int np = MPAD / 128;               // 391 row panels
    int g512 = np * 4, g256 = np * 2;  // 1D grids, XCD-remapped in-kernel
    int nwb = (NNODES + 3) / 4;

    // GAT layer 1 (logits from folded weights, before the GEMM)
    k_logits_pre<<<nwb, blk, 0, stream>>>(xb, wsd1, als, ald, 192);
    gemm64<EPI_BF><<<g512, blk, 0, stream>>>((const ushort*)xb, (const ushort*)W1t,
        nullptr, bufA, nullptr, nullptr, NNODES, 512, 192, nullptr, 4);
    k_edge_alpha<<<nwb, blk, 0, stream>>>(als, ald, offs, srcs, alpha);
    k_gat_aggregate<<<nwb, blk, 0, stream>>>(bufA, alpha, offs, srcs, b1, g1, bn1, bufB);

    // expansion MLP + residual combine (fused dual GEMM)
    gemm64<EPI_BRELU_BF><<<g512, blk, 0, stream>>>((const ushort*)bufB, (const ushort*)We1t,
        bE1, bufC, nullptr, nullptr, NNODES, 512, 512, nullptr, 4);
    gemm_dual64<<<g256, blk, 0, stream>>>((const ushort*)bufC, (const ushort*)We2t,
        (const ushort*)bufB, (const ushort*)Wrt, bE2, br, hcb, NNODES, 256, 512, rsc, 2);

    // GAT layer 2
    k_logits_pre<<<nwb, blk, 0, stream>>>(hcb, wsd2, als, ald, 256);
    gemm64<EPI_BF><<<g512, blk, 0, stream>>>((const ushort*)hcb, (const ushort*)W2t,
        nullptr, bufA, nullptr, nullptr, NNODES, 512, 256, nullptr, 4);
    k_edge_alpha<<<nwb, blk, 0, stream>>>(als, ald, offs, srcs, alpha);
    k_gat_aggregate<<<nwb, blk, 0, stream>>>(bufA, alpha, offs, srcs, b2, g2, bn2, bufB);

    // classifier fused into Wc1 GEMM epilogue
    hipMemsetAsync(out, 0, (size_t)out_size * 4, stream);
    gemm64<EPI_CLS><<<g512, blk, 0, stream>>>((const ushort*)bufB, (const ushort*)Wc1t,
        bc1, nullptr, out, Wc2, NNODES, 512, 512, bc2, 4);
}

// Round 13
// 509.509 us; speedup vs baseline: 1.1921x; 1.1921x over previous
//
#include <hip/hip_runtime.h>
#include <hip/hip_bf16.h>
#include <math.h>

#define NNODES 50000
#define NEDGES 500000
#define NTOT   (NEDGES + NNODES)   // 550000 edges incl. self-loops
#define MPAD   50048               // 391 * 128
#define D1     512
#define NH     4
#define LN_EPS 1e-5f
#define NEG_SLOPE 0.2f

#define SBLK 256
#define NSB  ((NNODES + SBLK - 1) / SBLK)   // 196

typedef __attribute__((ext_vector_type(8))) short short8;
typedef __attribute__((ext_vector_type(4))) float f32x4;
typedef __hip_bfloat16 bf16;

#define GLDS16(g, l) __builtin_amdgcn_global_load_lds( \
    (const __attribute__((address_space(1))) void*)(g), \
    (__attribute__((address_space(3))) void*)(l), 16, 0, 0)

__device__ __forceinline__ float bf2f(short u) {
    unsigned int x = ((unsigned int)(unsigned short)u) << 16;
    return __uint_as_float(x);
}
__device__ __forceinline__ short f2bf(float f) {   // RNE
    unsigned int x = __float_as_uint(f);
    unsigned int r = (x + 0x7fffu + ((x >> 16) & 1u)) >> 16;
    return (short)r;
}
__device__ __forceinline__ float leaky(float e) {
    return (e >= 0.f) ? e : NEG_SLOPE * e;
}

// bijective XCD-chunked remap (m204): consecutive work-ids land on one XCD,
// col-block fastest, so a panel's col-blocks share that XCD's L2 (A reuse).
__device__ __forceinline__ void xcd_map(int bid, int nwg, int ncolblk,
                                        int* p, int* c) {
    int q = nwg >> 3, r = nwg & 7;
    int xcd = bid & 7, j = bid >> 3;
    int w = (xcd < r) ? xcd * (q + 1) + j : r * (q + 1) + (xcd - r) * q + j;
    *p = w / ncolblk;
    *c = w - (*p) * ncolblk;
}

// ---------------- CSR build (counting sort by dst) ----------------

__global__ void k_count(const int* __restrict__ ei, int* __restrict__ counts) {
    int e = blockIdx.x * blockDim.x + threadIdx.x;
    if (e >= NTOT) return;
    int d = (e < NEDGES) ? ei[NEDGES + e] : (e - NEDGES);
    atomicAdd(&counts[d], 1);
}

__global__ void k_scan1(const int* __restrict__ counts, int* __restrict__ offs,
                        int* __restrict__ bsums) {
    __shared__ int s[SBLK];
    int tid = threadIdx.x, b = blockIdx.x;
    int idx = b * SBLK + tid;
    int v = (idx < NNODES) ? counts[idx] : 0;
    s[tid] = v;
    __syncthreads();
    for (int d = 1; d < SBLK; d <<= 1) {
        int t = (tid >= d) ? s[tid - d] : 0;
        __syncthreads();
        s[tid] += t;
        __syncthreads();
    }
    if (idx < NNODES) offs[idx] = s[tid] - v;   // local exclusive
    if (tid == SBLK - 1) bsums[b] = s[tid];
}

__global__ void k_scan2(const int* __restrict__ bsums, int* __restrict__ bbase) {
    __shared__ int s[256];
    int tid = threadIdx.x;
    int v = (tid < NSB) ? bsums[tid] : 0;
    s[tid] = v;
    __syncthreads();
    for (int d = 1; d < 256; d <<= 1) {
        int t = (tid >= d) ? s[tid - d] : 0;
        __syncthreads();
        s[tid] += t;
        __syncthreads();
    }
    bbase[tid] = s[tid] - v;                     // exclusive
    if (tid == 255) bbase[256] = s[255];         // total
}

__global__ void k_scan3(int* __restrict__ offs, const int* __restrict__ bbase,
                        int* __restrict__ cursor) {
    int idx = blockIdx.x * 256 + threadIdx.x;
    if (idx < NNODES) {
        int v = offs[idx] + bbase[idx >> 8];
        offs[idx] = v;
        cursor[idx] = v;
    }
    if (idx == 0) offs[NNODES] = bbase[256];
}

__global__ void k_fill(const int* __restrict__ ei, int* __restrict__ cursor,
                       int* __restrict__ srcs) {
    int e = blockIdx.x * blockDim.x + threadIdx.x;
    if (e >= NTOT) return;
    int s, d;
    if (e < NEDGES) { s = ei[e]; d = ei[NEDGES + e]; }
    else            { s = d = e - NEDGES; }
    int pos = atomicAdd(&cursor[d], 1);
    srcs[pos] = s;
}

// ---------------- conversions ----------------

__global__ void k_wt_all(const float* __restrict__ W1, const float* __restrict__ We1,
                         const float* __restrict__ We2, const float* __restrict__ Wr,
                         const float* __restrict__ W2, const float* __restrict__ Wc1,
                         bf16* __restrict__ W1t, bf16* __restrict__ We1t,
                         bf16* __restrict__ We2t, bf16* __restrict__ Wrt,
                         bf16* __restrict__ W2t, bf16* __restrict__ Wc1t) {
    int which = blockIdx.y;
    const float* W; bf16* Wt; int K, N, Kpad;
    switch (which) {
        case 0:  W = W1;  Wt = W1t;  K = 182; N = 512; Kpad = 192; break;
        case 1:  W = We1; Wt = We1t; K = 512; N = 512; Kpad = 512; break;
        case 2:  W = We2; Wt = We2t; K = 512; N = 256; Kpad = 512; break;
        case 3:  W = Wr;  Wt = Wrt;  K = 512; N = 256; Kpad = 512; break;
        case 4:  W = W2;  Wt = W2t;  K = 256; N = 512; Kpad = 256; break;
        default: W = Wc1; Wt = Wc1t; K = 512; N = 512; Kpad = 512; break;
    }
    int idx = blockIdx.x * 256 + threadIdx.x;
    if (idx >= N * Kpad) return;
    int n = idx / Kpad, k = idx % Kpad;
    float v = (k < K) ? W[(size_t)k * N + n] : 0.f;
    Wt[idx] = __float2bfloat16(v);
}

__global__ void k_xconv(const float* __restrict__ x, bf16* __restrict__ xb) {
    int idx = blockIdx.x * 256 + threadIdx.x;
    if (idx >= MPAD * 192) return;
    int r = idx / 192, k = idx % 192;
    float v = (r < NNODES && k < 182) ? x[(size_t)r * 182 + k] : 0.f;
    xb[idx] = __float2bfloat16(v);
}

// ---------------- attention logits: als/ald [N,H] (one wave per node) --------

__global__ __launch_bounds__(256) void k_attn_logits(
        const bf16* __restrict__ h, const float* __restrict__ a_s,
        const float* __restrict__ a_d, float* __restrict__ als,
        float* __restrict__ ald) {
    int tid = threadIdx.x;
    int n = blockIdx.x * 4 + (tid >> 6);
    if (n >= NNODES) return;
    int lane = tid & 63;
    int ch0 = lane * 8;
    short8 hv = *reinterpret_cast<const short8*>(&h[(size_t)n * D1 + ch0]);
    float s1 = 0.f, s2 = 0.f;
    #pragma unroll
    for (int j = 0; j < 8; j++) {
        float v = bf2f(hv[j]);
        s1 += v * a_s[ch0 + j];
        s2 += v * a_d[ch0 + j];
    }
    #pragma unroll
    for (int o = 1; o < 16; o <<= 1) {
        s1 += __shfl_xor(s1, o);
        s2 += __shfl_xor(s2, o);
    }
    if ((lane & 15) == 0) {
        int head = lane >> 4;
        als[n * NH + head] = s1;
        ald[n * NH + head] = s2;
    }
}

// -------- per-edge softmax alpha (one wave per node, edge-parallel) ---------

__global__ __launch_bounds__(256) void k_edge_alpha(
        const float* __restrict__ als, const float* __restrict__ ald,
        const int* __restrict__ offs, const int* __restrict__ srcs,
        float* __restrict__ alpha) {
    int tid = threadIdx.x;
    int n = blockIdx.x * 4 + (tid >> 6);
    if (n >= NNODES) return;
    int lane = tid & 63;
    int head = lane >> 4, sub = lane & 15;
    int e0 = offs[n], e1 = offs[n + 1];
    float adh = ald[n * NH + head];

    float m = -1e30f;
    for (int k = e0 + sub; k < e1; k += 16)
        m = fmaxf(m, leaky(als[srcs[k] * NH + head] + adh));
    #pragma unroll
    for (int o = 1; o < 16; o <<= 1) m = fmaxf(m, __shfl_xor(m, o));
    float d = 0.f;
    for (int k = e0 + sub; k < e1; k += 16)
        d += __expf(leaky(als[srcs[k] * NH + head] + adh) - m);
    #pragma unroll
    for (int o = 1; o < 16; o <<= 1) d += __shfl_xor(d, o);
    float dinv = 1.f / d;
    for (int k = e0 + sub; k < e1; k += 16)
        alpha[k * NH + head] = __expf(leaky(als[srcs[k] * NH + head] + adh) - m) * dinv;
}

// ------ GAT aggregation + bias + LayerNorm + ELU (one wave per node) --------

__global__ __launch_bounds__(256) void k_gat_aggregate(
        const bf16* __restrict__ h, const float* __restrict__ alpha,
        const int* __restrict__ offs, const int* __restrict__ srcs,
        const float* __restrict__ bias, const float* __restrict__ gamma,
        const float* __restrict__ beta, bf16* __restrict__ out) {
    int tid = threadIdx.x;
    int n = blockIdx.x * 4 + (tid >> 6);
    if (n >= NNODES) return;
    int lane = tid & 63;
    int head = lane >> 4;
    int ch0 = lane * 8;
    int e0 = offs[n], e1 = offs[n + 1];

    float acc[8] = {};
    for (int base = e0; base < e1; base += 64) {
        int cnt = min(64, e1 - base);
        int sv = (base + lane < e1) ? srcs[base + lane] : 0;
        int k = 0;
        for (; k + 8 <= cnt; k += 8) {
            int ss[8]; float pp[8]; short8 hh[8];
            #pragma unroll
            for (int u = 0; u < 8; u++) {
                ss[u] = __shfl(sv, k + u);
                pp[u] = alpha[(base + k + u) * NH + head];
            }
            #pragma unroll
            for (int u = 0; u < 8; u++)
                hh[u] = *reinterpret_cast<const short8*>(&h[(size_t)ss[u] * D1 + ch0]);
            #pragma unroll
            for (int j = 0; j < 8; j++) {
                float a = 0.f;
                #pragma unroll
                for (int u = 0; u < 8; u++) a += pp[u] * bf2f(hh[u][j]);
                acc[j] += a;
            }
        }
        for (; k + 4 <= cnt; k += 4) {
            int s0 = __shfl(sv, k),     s1 = __shfl(sv, k + 1);
            int s2 = __shfl(sv, k + 2), s3 = __shfl(sv, k + 3);
            float p0 = alpha[(base + k)     * NH + head];
            float p1 = alpha[(base + k + 1) * NH + head];
            float p2 = alpha[(base + k + 2) * NH + head];
            float p3 = alpha[(base + k + 3) * NH + head];
            short8 h0 = *reinterpret_cast<const short8*>(&h[(size_t)s0 * D1 + ch0]);
            short8 h1 = *reinterpret_cast<const short8*>(&h[(size_t)s1 * D1 + ch0]);
            short8 h2 = *reinterpret_cast<const short8*>(&h[(size_t)s2 * D1 + ch0]);
            short8 h3 = *reinterpret_cast<const short8*>(&h[(size_t)s3 * D1 + ch0]);
            #pragma unroll
            for (int j = 0; j < 8; j++)
                acc[j] += p0 * bf2f(h0[j]) + p1 * bf2f(h1[j])
                        + p2 * bf2f(h2[j]) + p3 * bf2f(h3[j]);
        }
        for (; k < cnt; k++) {
            int s0 = __shfl(sv, k);
            float p0 = alpha[(base + k) * NH + head];
            short8 h0 = *reinterpret_cast<const short8*>(&h[(size_t)s0 * D1 + ch0]);
            #pragma unroll
            for (int j = 0; j < 8; j++) acc[j] += p0 * bf2f(h0[j]);
        }
    }

    float v[8];
    float ps = 0.f;
    #pragma unroll
    for (int j = 0; j < 8; j++) { v[j] = acc[j] + bias[ch0 + j]; ps += v[j]; }
    #pragma unroll
    for (int o = 1; o < 64; o <<= 1) ps += __shfl_xor(ps, o);
    float mu = ps * (1.f / 512.f);
    float qs = 0.f;
    #pragma unroll
    for (int j = 0; j < 8; j++) { float dvj = v[j] - mu; qs += dvj * dvj; }
    #pragma unroll
    for (int o = 1; o < 64; o <<= 1) qs += __shfl_xor(qs, o);
    float rstd = rsqrtf(qs * (1.f / 512.f) + LN_EPS);

    short8 ov;
    #pragma unroll
    for (int j = 0; j < 8; j++) {
        float y = (v[j] - mu) * rstd * gamma[ch0 + j] + beta[ch0 + j];
        float e = (y > 0.f) ? y : (__expf(y) - 1.f);
        ov[j] = f2bf(e);
    }
    *reinterpret_cast<short8*>(&out[(size_t)n * D1 + ch0]) = ov;
}

// ---------------- bf16 MFMA GEMM, BK=64, both-sides swizzled LDS ------------
// 1D grid + XCD-chunked block remap (T1): a panel's col-blocks colocate.

#define EPI_BF       0   // C -> bf16
#define EPI_BRELU_BF 1   // relu(C + bias) -> bf16
#define EPI_CLS      2   // atomicAdd(out, relu(C+bias) @ Wc2 (+bc2))

template<int EPI>
__global__ __launch_bounds__(256) void gemm64(
    const ushort* __restrict__ A, const ushort* __restrict__ Bt,
    const float* __restrict__ bias, bf16* __restrict__ Obf,
    float* __restrict__ Of32, const float* __restrict__ Wc2,
    int Mreal, int N, int K, const float* __restrict__ bc2, int ncolblk) {
    __shared__ __align__(16) ushort As[128 * 64];
    __shared__ __align__(16) ushort Bs[128 * 64];
    int tid = threadIdx.x;
    int wave = tid >> 6, lane = tid & 63;
    int pp, cc;
    xcd_map(blockIdx.x, gridDim.x, ncolblk, &pp, &cc);
    int brow = pp * 128;
    int bcol = cc * 128;
    int wm = (wave >> 1) * 64, wn = (wave & 1) * 64;
    int lr = lane & 15, hi = lane >> 4;
    int rx = lr & 7;                 // read-side row xor
    int r8 = lane >> 3;              // stage-side row within 8-row group
    int slotsw = (lane & 7) ^ r8;    // pre-swizzled 16B slot in global row

    f32x4 acc[4][4] = {};

    for (int k0 = 0; k0 < K; k0 += 64) {
        if (k0) __syncthreads();
        #pragma unroll
        for (int i = 0; i < 4; i++) {
            int rb = wave * 32 + i * 8;     // 8 rows per GLDS16 (1 KB)
            GLDS16(A  + (size_t)(brow + rb + r8) * K + k0 + slotsw * 8, As + rb * 64);
            GLDS16(Bt + (size_t)(bcol + rb + r8) * K + k0 + slotsw * 8, Bs + rb * 64);
        }
        __syncthreads();

        #pragma unroll
        for (int sub = 0; sub < 2; sub++) {
            short8 af[4], bfr[4];
            int bsl = ((sub * 4 + hi) ^ rx) * 8;
            #pragma unroll
            for (int f = 0; f < 4; f++) {
                af[f]  = *reinterpret_cast<const short8*>(&As[(wm + f * 16 + lr) * 64 + bsl]);
                bfr[f] = *reinterpret_cast<const short8*>(&Bs[(wn + f * 16 + lr) * 64 + bsl]);
            }
            #pragma unroll
            for (int fm = 0; fm < 4; fm++)
                #pragma unroll
                for (int fn = 0; fn < 4; fn++)
                    acc[fm][fn] = __builtin_amdgcn_mfma_f32_16x16x32_bf16(
                        af[fm], bfr[fn], acc[fm][fn], 0, 0, 0);
        }
    }

    if (EPI == EPI_CLS) {
        float w2[4][2], b4[4];
        #pragma unroll
        for (int fn = 0; fn < 4; fn++) {
            int col = bcol + wn + fn * 16 + lr;
            w2[fn][0] = Wc2[col * 2];
            w2[fn][1] = Wc2[col * 2 + 1];
            b4[fn] = bias[col];
        }
        #pragma unroll
        for (int fm = 0; fm < 4; fm++) {
            #pragma unroll
            for (int r = 0; r < 4; r++) {
                int row = brow + wm + fm * 16 + hi * 4 + r;
                float s0 = 0.f, s1 = 0.f;
                #pragma unroll
                for (int fn = 0; fn < 4; fn++) {
                    float v = acc[fm][fn][r] + b4[fn];
                    v = v > 0.f ? v : 0.f;
                    s0 += v * w2[fn][0];
                    s1 += v * w2[fn][1];
                }
                #pragma unroll
                for (int o = 1; o < 16; o <<= 1) {
                    s0 += __shfl_xor(s0, o);
                    s1 += __shfl_xor(s1, o);
                }
                if (lr == 0 && row < Mreal) {
                    if (bcol == 0 && wn == 0) { s0 += bc2[0]; s1 += bc2[1]; }
                    atomicAdd(&Of32[row * 2],     s0);
                    atomicAdd(&Of32[row * 2 + 1], s1);
                }
            }
        }
        return;
    }

    #pragma unroll
    for (int fm = 0; fm < 4; fm++) {
        int row0 = brow + wm + fm * 16 + hi * 4;
        #pragma unroll
        for (int fn = 0; fn < 4; fn++) {
            int col = bcol + wn + fn * 16 + lr;
            #pragma unroll
            for (int r = 0; r < 4; r++) {
                int row = row0 + r;
                if (row >= Mreal) continue;
                float v = acc[fm][fn][r];
                if (EPI == EPI_BRELU_BF) { v += bias[col]; v = v > 0.f ? v : 0.f; }
                Obf[(size_t)row * N + col] = __float2bfloat16(v);
            }
        }
    }
}

// ------- dual GEMM (BK=64): O = A2@B2t + rs*(A1@B1t) + (b2 + rs*b1) -> bf16 --

__global__ __launch_bounds__(256) void gemm_dual64(
    const ushort* __restrict__ A1, const ushort* __restrict__ B1t,   // t, We2t
    const ushort* __restrict__ A2, const ushort* __restrict__ B2t,   // h1, Wrt
    const float* __restrict__ bias1, const float* __restrict__ bias2,
    bf16* __restrict__ Obf, int Mreal, int N, int K,
    const float* __restrict__ rsc, int ncolblk) {
    __shared__ __align__(16) ushort As[128 * 64];
    __shared__ __align__(16) ushort Bs[128 * 64];
    int tid = threadIdx.x;
    int wave = tid >> 6, lane = tid & 63;
    int pp, cc;
    xcd_map(blockIdx.x, gridDim.x, ncolblk, &pp, &cc);
    int brow = pp * 128;
    int bcol = cc * 128;
    int wm = (wave >> 1) * 64, wn = (wave & 1) * 64;
    int lr = lane & 15, hi = lane >> 4;
    int rx = lr & 7;
    int r8 = lane >> 3;
    int slotsw = (lane & 7) ^ r8;
    float rs = *rsc;

    f32x4 acc[4][4] = {};

    #pragma unroll
    for (int phase = 0; phase < 2; phase++) {
        const ushort* Ap = phase ? A2 : A1;
        const ushort* Bp = phase ? B2t : B1t;
        if (phase) {
            __syncthreads();
            #pragma unroll
            for (int fm = 0; fm < 4; fm++)
                #pragma unroll
                for (int fn = 0; fn < 4; fn++)
                    #pragma unroll
                    for (int r = 0; r < 4; r++) acc[fm][fn][r] *= rs;
        }
        for (int k0 = 0; k0 < K; k0 += 64) {
            if (k0 || phase) __syncthreads();
            #pragma unroll
            for (int i = 0; i < 4; i++) {
                int rb = wave * 32 + i * 8;
                GLDS16(Ap + (size_t)(brow + rb + r8) * K + k0 + slotsw * 8, As + rb * 64);
                GLDS16(Bp + (size_t)(bcol + rb + r8) * K + k0 + slotsw * 8, Bs + rb * 64);
            }
            __syncthreads();

            #pragma unroll
            for (int sub = 0; sub < 2; sub++) {
                short8 af[4], bfr[4];
                int bsl = ((sub * 4 + hi) ^ rx) * 8;
                #pragma unroll
                for (int f = 0; f < 4; f++) {
                    af[f]  = *reinterpret_cast<const short8*>(&As[(wm + f * 16 + lr) * 64 + bsl]);
                    bfr[f] = *reinterpret_cast<const short8*>(&Bs[(wn + f * 16 + lr) * 64 + bsl]);
                }
                #pragma unroll
                for (int fm = 0; fm < 4; fm++)
                    #pragma unroll
                    for (int fn = 0; fn < 4; fn++)
                        acc[fm][fn] = __builtin_amdgcn_mfma_f32_16x16x32_bf16(
                            af[fm], bfr[fn], acc[fm][fn], 0, 0, 0);
            }
        }
    }

    #pragma unroll
    for (int fm = 0; fm < 4; fm++) {
        int row0 = brow + wm + fm * 16 + hi * 4;
        #pragma unroll
        for (int fn = 0; fn < 4; fn++) {
            int col = bcol + wn + fn * 16 + lr;
            float be = bias2[col] + rs * bias1[col];
            #pragma unroll
            for (int r = 0; r < 4; r++) {
                int row = row0 + r;
                if (row >= Mreal) continue;
                Obf[(size_t)row * N + col] = __float2bfloat16(acc[fm][fn][r] + be);
            }
        }
    }
}

// ---------------- launch ----------------

extern "C" void kernel_launch(void* const* d_in, const int* in_sizes, int n_in,
                              void* d_out, int out_size, void* d_ws, size_t ws_size,
                              hipStream_t stream) {
    const float* x   = (const float*)d_in[0];
    const int*   ei  = (const int*)d_in[1];
    const float* W1  = (const float*)d_in[2];
    const float* as1 = (const float*)d_in[3];
    const float* ad1 = (const float*)d_in[4];
    const float* b1  = (const float*)d_in[5];
    const float* g1  = (const float*)d_in[6];
    const float* bn1 = (const float*)d_in[7];
    const float* We1 = (const float*)d_in[8];
    const float* bE1 = (const float*)d_in[9];
    const float* We2 = (const float*)d_in[10];
    const float* bE2 = (const float*)d_in[11];
    const float* Wr  = (const float*)d_in[12];
    const float* br  = (const float*)d_in[13];
    const float* rsc = (const float*)d_in[14];
    const float* W2  = (const float*)d_in[15];
    const float* as2 = (const float*)d_in[16];
    const float* ad2 = (const float*)d_in[17];
    const float* b2  = (const float*)d_in[18];
    const float* g2  = (const float*)d_in[19];
    const float* bn2 = (const float*)d_in[20];
    const float* Wc1 = (const float*)d_in[21];
    const float* bc1 = (const float*)d_in[22];
    const float* Wc2 = (const float*)d_in[23];
    const float* bc2 = (const float*)d_in[24];
    float* out = (float*)d_out;

    char* ws = (char*)d_ws;
    size_t o = 0;
    auto alloc = [&](size_t bytes) { void* p = ws + o; o += (bytes + 255) & ~255ull; return p; };
    bf16* xb    = (bf16*)alloc((size_t)MPAD * 192 * 2);
    bf16* bufA  = (bf16*)alloc((size_t)MPAD * D1 * 2);   // h (per layer)
    bf16* bufB  = (bf16*)alloc((size_t)MPAD * D1 * 2);   // h1, h2
    bf16* bufC  = (bf16*)alloc((size_t)MPAD * D1 * 2);   // t (expansion)
    bf16* hcb   = (bf16*)alloc((size_t)MPAD * 256 * 2);  // h_comb bf16
    bf16* W1t   = (bf16*)alloc((size_t)512 * 192 * 2);
    bf16* We1t  = (bf16*)alloc((size_t)512 * 512 * 2);
    bf16* We2t  = (bf16*)alloc((size_t)256 * 512 * 2);
    bf16* Wrt   = (bf16*)alloc((size_t)256 * 512 * 2);
    bf16* W2t   = (bf16*)alloc((size_t)512 * 256 * 2);
    bf16* Wc1t  = (bf16*)alloc((size_t)512 * 512 * 2);
    float* als  = (float*)alloc((size_t)NNODES * NH * 4);
    float* ald  = (float*)alloc((size_t)NNODES * NH * 4);
    float* alpha= (float*)alloc((size_t)NTOT * NH * 4);
    int* counts = (int*)alloc((NNODES + 1) * 4);
    int* offs   = (int*)alloc((NNODES + 1) * 4);
    int* cursor = (int*)alloc((NNODES + 1) * 4);
    int* srcs   = (int*)alloc((size_t)NTOT * 4);
    int* bsums  = (int*)alloc((NSB + 1) * 4);
    int* bbase  = (int*)alloc(257 * 4);

    // CSR by dst (shared by both GAT layers)
    hipMemsetAsync(counts, 0, NNODES * 4, stream);
    k_count<<<(NTOT + 255) / 256, 256, 0, stream>>>(ei, counts);
    k_scan1<<<NSB, SBLK, 0, stream>>>(counts, offs, bsums);
    k_scan2<<<1, 256, 0, stream>>>(bsums, bbase);
    k_scan3<<<(NNODES + 255) / 256, 256, 0, stream>>>(offs, bbase, cursor);
    k_fill<<<(NTOT + 255) / 256, 256, 0, stream>>>(ei, cursor, srcs);

    // weight + input conversion
    k_wt_all<<<dim3(1024, 6), 256, 0, stream>>>(W1, We1, We2, Wr, W2, Wc1,
                                                W1t, We1t, We2t, Wrt, W2t, Wc1t);
    k_xconv<<<(MPAD * 192 + 255) / 256, 256, 0, stream>>>(x, xb);

    dim3 blk(256);
    int np = MPAD / 128;               // 391 row panels
    int g512 = np * 4, g256 = np * 2;  // 1D grids, XCD-remapped in-kernel
    int nwb = (NNODES + 3) / 4;

    // GAT layer 1
    gemm64<EPI_BF><<<g512, blk, 0, stream>>>((const ushort*)xb, (const ushort*)W1t,
        nullptr, bufA, nullptr, nullptr, NNODES, 512, 192, nullptr, 4);
    k_attn_logits<<<nwb, blk, 0, stream>>>(bufA, as1, ad1, als, ald);
    k_edge_alpha<<<nwb, blk, 0, stream>>>(als, ald, offs, srcs, alpha);
    k_gat_aggregate<<<nwb, blk, 0, stream>>>(bufA, alpha, offs, srcs, b1, g1, bn1, bufB);

    // expansion MLP + residual combine (fused dual GEMM)
    gemm64<EPI_BRELU_BF><<<g512, blk, 0, stream>>>((const ushort*)bufB, (const ushort*)We1t,
        bE1, bufC, nullptr, nullptr, NNODES, 512, 512, nullptr, 4);
    gemm_dual64<<<g256, blk, 0, stream>>>((const ushort*)bufC, (const ushort*)We2t,
        (const ushort*)bufB, (const ushort*)Wrt, bE2, br, hcb, NNODES, 256, 512, rsc, 2);

    // GAT layer 2
    gemm64<EPI_BF><<<g512, blk, 0, stream>>>((const ushort*)hcb, (const ushort*)W2t,
        nullptr, bufA, nullptr, nullptr, NNODES, 512, 256, nullptr, 4);
    k_attn_logits<<<nwb, blk, 0, stream>>>(bufA, as2, ad2, als, ald);
    k_edge_alpha<<<nwb, blk, 0, stream>>>(als, ald, offs, srcs, alpha);
    k_gat_aggregate<<<nwb, blk, 0, stream>>>(bufA, alpha, offs, srcs, b2, g2, bn2, bufB);

    // classifier fused into Wc1 GEMM epilogue
    hipMemsetAsync(out, 0, (size_t)out_size * 4, stream);
    gemm64<EPI_CLS><<<g512, blk, 0, stream>>>((const ushort*)bufB, (const ushort*)Wc1t,
        bc1, nullptr, out, Wc2, NNODES, 512, 512, bc2, 4);
}